// Round 14
// baseline (137.179 us; speedup 1.0000x reference)
//
#include <hip/hip_runtime.h>
#include <math.h>

// Problem constants
#define KP   10      // prototypes per side
#define CC   768     // channels
#define NB   8       // batch
#define HW   4096    // 64*64
#define STOT 32768   // NB*HW
#define NS   12      // N_SAMPLES
#define NBLK 256     // k_scores blocks (128 px each)

// Workspace layout (float offsets)
#define WS_CAND  0       // 2 sides x 256 blocks x 12 u64 = 6144 ull = 12288 floats
#define WS_FEATS 12352   // 24*768 floats (pos 12 rows, then neg 12 rows)
#define WS_PFG   30784   // 10*768
#define WS_PBG   38464   // 10*768

typedef unsigned long long ull;
typedef float f2v __attribute__((ext_vector_type(2)));

// packed 2-wide fma (v_pk_fma_f32); per-component order identical to scalar fmaf
__device__ __forceinline__ f2v fma2(f2v a, float b, f2v c) {
#if __has_builtin(__builtin_elementwise_fma)
    f2v bb = b;
    return __builtin_elementwise_fma(a, bb, c);
#else
    f2v r; r.x = fmaf(a.x, b, c.x); r.y = fmaf(a.y, b, c.y); return r;
#endif
}

// Order-preserving float->uint map, packed with ~index: exact
// (value desc, index asc) under unsigned max; unique per pixel; 0 = empty.
__device__ __forceinline__ ull pack_key(float v, int idx) {
    unsigned u = __float_as_uint(v);
    u ^= (unsigned)((int)u >> 31) | 0x80000000u;
    return ((ull)u << 32) | (ull)(0xFFFFFFFFu - (unsigned)idx);
}

// ---------------- K1: scores + per-block top-12 candidates ----------------
// (unchanged from R13: packed-f32 accumulators, LDS protos, nt F loads,
//  barrier-free per-block selection)
__global__ __launch_bounds__(1024) void k_scores(const float* __restrict__ fg,
                                                 const float* __restrict__ bg,
                                                 const float* __restrict__ F,
                                                 const float* __restrict__ M,
                                                 ull* __restrict__ cand) {
    __shared__ float pl[20 * CC];           // 61440 B
    __shared__ float part[8][64][2][21];    // 86016 B
    __shared__ ull kfl[128], kbl[128];      // 2048 B

    const int tid  = threadIdx.x;
    const int w    = __builtin_amdgcn_readfirstlane(tid >> 6);  // wave 0..15
    const int lane = tid & 63;
    const int b    = blockIdx.x;            // 0..255
    const int n    = b >> 5;                // 32 blocks per image
    const int hwb  = (b & 31) * 128 + lane * 2;
    const float* fp = F + ((size_t)n * CC) * HW + hwb;
    const int cbase = w * 48;

    f2v fnA[8], fnB[8];
#pragma unroll
    for (int j = 0; j < 8; ++j)
        fnA[j] = __builtin_nontemporal_load((const f2v*)(fp + (size_t)(cbase + j) * HW));
#pragma unroll
    for (int j = 0; j < 8; ++j)
        fnB[j] = __builtin_nontemporal_load((const f2v*)(fp + (size_t)(cbase + 8 + j) * HW));

    for (int i = tid; i < KP * CC; i += 1024) {
        pl[i]           = fg[i];
        pl[KP * CC + i] = bg[i];
    }
    __syncthreads();

    f2v afg[KP], abg[KP], n2;
#pragma unroll
    for (int k = 0; k < KP; ++k) { afg[k] = 0.f; abg[k] = 0.f; }
    n2 = 0.f;

    for (int c0 = 0; c0 < 48; c0 += 8) {
        f2v f[8];
#pragma unroll
        for (int j = 0; j < 8; ++j) { f[j] = fnA[j]; fnA[j] = fnB[j]; }
        if (c0 + 16 < 48) {
#pragma unroll
            for (int j = 0; j < 8; ++j)
                fnB[j] = __builtin_nontemporal_load((const f2v*)(fp + (size_t)(cbase + c0 + 16 + j) * HW));
        }

#pragma unroll
        for (int k = 0; k < KP; ++k) {
            const float4* pq = (const float4*)&pl[k * CC + cbase + c0];
            float4 a = pq[0], c = pq[1];
            f2v acc = afg[k];
            acc = fma2(f[0], a.x, acc); acc = fma2(f[1], a.y, acc);
            acc = fma2(f[2], a.z, acc); acc = fma2(f[3], a.w, acc);
            acc = fma2(f[4], c.x, acc); acc = fma2(f[5], c.y, acc);
            acc = fma2(f[6], c.z, acc); acc = fma2(f[7], c.w, acc);
            afg[k] = acc;
        }
#pragma unroll
        for (int k = 0; k < KP; ++k) {
            const float4* pq = (const float4*)&pl[(KP + k) * CC + cbase + c0];
            float4 a = pq[0], c = pq[1];
            f2v acc = abg[k];
            acc = fma2(f[0], a.x, acc); acc = fma2(f[1], a.y, acc);
            acc = fma2(f[2], a.z, acc); acc = fma2(f[3], a.w, acc);
            acc = fma2(f[4], c.x, acc); acc = fma2(f[5], c.y, acc);
            acc = fma2(f[6], c.z, acc); acc = fma2(f[7], c.w, acc);
            abg[k] = acc;
        }
#pragma unroll
        for (int j = 0; j < 8; ++j) {
#if __has_builtin(__builtin_elementwise_fma)
            n2 = __builtin_elementwise_fma(f[j], f[j], n2);
#else
            n2.x = fmaf(f[j].x, f[j].x, n2.x); n2.y = fmaf(f[j].y, f[j].y, n2.y);
#endif
        }
    }

    if (w >= 8) {
#pragma unroll
        for (int k = 0; k < KP; ++k) {
            part[w - 8][lane][0][k]      = afg[k].x; part[w - 8][lane][1][k]      = afg[k].y;
            part[w - 8][lane][0][10 + k] = abg[k].x; part[w - 8][lane][1][10 + k] = abg[k].y;
        }
        part[w - 8][lane][0][20] = n2.x; part[w - 8][lane][1][20] = n2.y;
    }
    __syncthreads();
    if (w < 8) {
#pragma unroll
        for (int k = 0; k < KP; ++k) {
            part[w][lane][0][k]      += afg[k].x; part[w][lane][1][k]      += afg[k].y;
            part[w][lane][0][10 + k] += abg[k].x; part[w][lane][1][10 + k] += abg[k].y;
        }
        part[w][lane][0][20] += n2.x; part[w][lane][1][20] += n2.y;
    }
    __syncthreads();

    if (tid < 128) {
        const int lane2 = tid >> 1, j = tid & 1;
        float vals[21];
#pragma unroll
        for (int q = 0; q < 21; ++q) {
            float acc = 0.f;
#pragma unroll
            for (int ss = 0; ss < 8; ++ss) acc += part[ss][lane2][j][q];
            vals[q] = acc;
        }
        float mfg = vals[0], mbg = vals[10];
#pragma unroll
        for (int k = 1; k < KP; ++k) { mfg = fmaxf(mfg, vals[k]); mbg = fmaxf(mbg, vals[10 + k]); }
        float nc = fmaxf(sqrtf(vals[20]), 1e-8f);
        int sp = b * 128 + tid;
        float m = fminf(fmaxf(M[sp], 0.f), 1.f);
        kfl[tid] = pack_key((1.f - mfg / nc) * m, sp);
        kbl[tid] = pack_key((1.f - mbg / nc) * (1.f - m), sp);
    }
    __syncthreads();

    if (w == 0) {
        ull k0 = kfl[lane], k1 = kfl[64 + lane];
        for (int r = 0; r < NS; ++r) {
            ull bk = (k0 > k1) ? k0 : k1;
#pragma unroll
            for (int m2 = 1; m2 < 64; m2 <<= 1) {
                ull o = __shfl_xor(bk, m2, 64);
                bk = (o > bk) ? o : bk;
            }
            if (lane == 0) cand[b * NS + r] = bk;
            if (k0 == bk) k0 = 0ull;
            if (k1 == bk) k1 = 0ull;
        }
    } else if (w == 1) {
        ull k0 = kbl[lane], k1 = kbl[64 + lane];
        for (int r = 0; r < NS; ++r) {
            ull bk = (k0 > k1) ? k0 : k1;
#pragma unroll
            for (int m2 = 1; m2 < 64; m2 <<= 1) {
                ull o = __shfl_xor(bk, m2, 64);
                bk = (o > bk) ? o : bk;
            }
            if (lane == 0) cand[NBLK * NS + b * NS + r] = bk;
            if (k0 == bk) k0 = 0ull;
            if (k1 == bk) k1 = 0ull;
        }
    }
}

// ---- K2: fused merge + gather + normalize + GRAM-ACCELERATED refine + blend ----
// Refinement runs in the 12x12 Gram domain: per-iteration cost is scalar math
// on one wave (broadcast shuffles, no barriers); 768-dim work happens exactly
// twice (Gram setup + final reconstruction from tracked coefficients).
__global__ __launch_bounds__(1024) void k_refine_fused(const ull* __restrict__ cand,
                                                       const float* __restrict__ F,
                                                       const float* __restrict__ fg,
                                                       const float* __restrict__ bg,
                                                       float* __restrict__ pfg,
                                                       float* __restrict__ pbg,
                                                       float* __restrict__ feats,
                                                       float* __restrict__ out) {
    __shared__ float fe[NS * CC];    // 36 KB normalized sample rows
    __shared__ float p0l[KP * CC];   // 30 KB initial prototypes
    __shared__ int   seli[NS];
    __shared__ float D0sh[NS * KP];  // <fe_s, p0_k>
    __shared__ float Gsh[NS * NS];   // <fe_s, fe_s'>
    __shared__ float P2sh[KP];       // <p0_k, p0_k>
    __shared__ float coef[KP][13];   // alpha, beta[12]

    const int side = blockIdx.x;
    const int tid  = threadIdx.x;
    const int wave = __builtin_amdgcn_readfirstlane(tid >> 6);  // 0..15
    const int lane = tid & 63;
    const float* p0g = (side == 0) ? fg : bg;
    float* pout      = (side == 0) ? pfg : pbg;

    // ---- wave 0: merge 3072 candidates -> top-12; waves 1..15: stage p0l ----
    if (wave == 0) {
        const ull* cs = cand + side * (NBLK * NS);
        ull tv[NS];
#pragma unroll
        for (int q = 0; q < NS; ++q) tv[q] = 0ull;
        for (int c = 0; c < 48; ++c) {
            ull key = cs[c * 64 + lane];
            if (key > tv[NS - 1]) {
#pragma unroll
                for (int q = NS - 1; q >= 1; --q) {
                    bool shift = key > tv[q - 1];
                    bool here  = !shift && (key > tv[q]);
                    tv[q] = shift ? tv[q - 1] : (here ? key : tv[q]);
                }
                if (key > tv[0]) tv[0] = key;
            }
        }
        for (int r = 0; r < NS; ++r) {
            ull bk = tv[0];
#pragma unroll
            for (int m2 = 1; m2 < 64; m2 <<= 1) {
                ull o = __shfl_xor(bk, m2, 64);
                bk = (o > bk) ? o : bk;
            }
            if (lane == 0) seli[r] = (int)(0xFFFFFFFFu - (unsigned)(bk & 0xFFFFFFFFull));
            bool win = (tv[0] == bk);                // keys unique -> one lane
#pragma unroll
            for (int q = 0; q < NS - 1; ++q) tv[q] = win ? tv[q + 1] : tv[q];
            tv[NS - 1] = win ? 0ull : tv[NS - 1];
        }
    } else {
        for (int i = tid - 64; i < KP * CC; i += 960) p0l[i] = p0g[i];
    }
    __syncthreads();

    // ---- gather 12 rows x 768 channels into LDS ----
    for (int i = tid; i < NS * CC; i += 1024) {
        int srow = i / CC, c = i - srow * CC;
        int sp = seli[srow];
        int nn = sp >> 12, hh = sp & 4095;
        fe[i] = F[((size_t)nn * CC + c) * HW + hh];
    }
    __syncthreads();

    // ---- row-normalize in place: wave r handles row r ----
    if (wave < NS) {
        float ssq = 0.f;
#pragma unroll
        for (int j = 0; j < 12; ++j) { float v = fe[wave * CC + j * 64 + lane]; ssq = fmaf(v, v, ssq); }
#pragma unroll
        for (int m2 = 1; m2 < 64; m2 <<= 1) ssq += __shfl_xor(ssq, m2, 64);
        float inv = 1.f / fmaxf(sqrtf(ssq), 1e-8f);
#pragma unroll
        for (int j = 0; j < 12; ++j) fe[wave * CC + j * 64 + lane] *= inv;
    }
    __syncthreads();

    // ---- publish normalized feats for k_loss ----
    {
        float4* fo = (float4*)(feats + side * (NS * CC));
        const float4* fi = (const float4*)fe;
        for (int i = tid; i < NS * CC / 4; i += 1024) fo[i] = fi[i];
    }

    // ---- setup dots: 274 wave-dots across 16 waves ----
    for (int t = wave; t < 274; t += 16) {
        const float *A, *B; float* dst;
        if (t < 120)      { int s = t / 10, k = t - 10 * s; A = &fe[s * CC];  B = &p0l[k * CC]; dst = &D0sh[t]; }
        else if (t < 264) { int u = t - 120; int s = u / 12, s2 = u - 12 * s; A = &fe[s * CC]; B = &fe[s2 * CC]; dst = &Gsh[u]; }
        else              { int k = t - 264; A = &p0l[k * CC]; B = A; dst = &P2sh[k]; }
        const float4* A4 = (const float4*)A;
        const float4* B4 = (const float4*)B;
        float acc = 0.f;
#pragma unroll
        for (int j4 = 0; j4 < 3; ++j4) {
            float4 a = A4[j4 * 64 + lane], b = B4[j4 * 64 + lane];
            acc = fmaf(a.x, b.x, acc); acc = fmaf(a.y, b.y, acc);
            acc = fmaf(a.z, b.z, acc); acc = fmaf(a.w, b.w, acc);
        }
#pragma unroll
        for (int m2 = 1; m2 < 64; m2 <<= 1) acc += __shfl_xor(acc, m2, 64);
        if (lane == 0) *dst = acc;
    }
    __syncthreads();

    // ---- wave 0: 10 Gram-domain iterations (lane s<12 owns sample s;
    //      lane k<10 also owns proto k's coefficients). No barriers. ----
    if (wave == 0) {
        float d[KP], g[NS], p2[KP];
#pragma unroll
        for (int k = 0; k < KP; ++k) d[k] = (lane < NS) ? D0sh[lane * KP + k] : 0.f;
#pragma unroll
        for (int s = 0; s < NS; ++s) g[s] = (lane < NS) ? Gsh[lane * NS + s] : 0.f;
#pragma unroll
        for (int k = 0; k < KP; ++k) p2[k] = P2sh[k];
        float alpha = 1.f, beta[NS];
#pragma unroll
        for (int s = 0; s < NS; ++s) beta[s] = 0.f;

        for (int it = 0; it < 10; ++it) {
            float step = 0.1f / (1.0f + 0.5f * (float)it);
            float om = 1.0f - step;

            // argmax over k (strict > keeps first max, matches jnp.argmax)
            int aL = 0; float bv = d[0];
#pragma unroll
            for (int k = 1; k < KP; ++k) { if (d[k] > bv) { bv = d[k]; aL = k; } }

            // broadcast assignments + own-best dot from lanes 0..11
            int av[NS]; float vv[NS];
#pragma unroll
            for (int s = 0; s < NS; ++s) { av[s] = __shfl(aL, s, 64); vv[s] = __shfl(bv, s, 64); }

            // T_k[s] = sum_{s' in k} G[s][s']; W = T_{a_s}[s] (captured statically)
            float T[KP]; float W = 0.f;
#pragma unroll
            for (int k = 0; k < KP; ++k) {
                float t = 0.f;
#pragma unroll
                for (int s = 0; s < NS; ++s) t += (av[s] == k) ? g[s] : 0.f;
                T[k] = t;
                if (k == aL) W = t;
            }
            float wv[NS];
#pragma unroll
            for (int s = 0; s < NS; ++s) wv[s] = __shfl(W, s, 64);

            // per-k aggregates + dot update; capture own proto's params
            float mynorm = 1.f, mysc = 0.f; int mycnt = 0;
#pragma unroll
            for (int k = 0; k < KP; ++k) {
                int c = 0; float S1 = 0.f, U = 0.f;
#pragma unroll
                for (int s = 0; s < NS; ++s) {
                    bool m = (av[s] == k);
                    c += m ? 1 : 0;
                    S1 += m ? vv[s] : 0.f;
                    U  += m ? wv[s] : 0.f;
                }
                if (c > 0) {
                    float sc = step / (float)c;
                    float nv = om * om * p2[k] + 2.f * om * sc * S1 + sc * sc * U;
                    float nrm = fmaxf(sqrtf(fmaxf(nv, 0.f)), 1e-8f);
                    float inv = 1.f / nrm;
                    d[k] = (om * d[k] + sc * T[k]) * inv;
                    p2[k] = 1.f;
                    if (k == lane) { mynorm = inv; mysc = sc; mycnt = c; }
                }
            }

            // coefficient update for own proto (lane < KP)
            if (lane < KP && mycnt > 0) {
                alpha *= om * mynorm;
#pragma unroll
                for (int s = 0; s < NS; ++s)
                    beta[s] = (om * beta[s] + ((av[s] == lane) ? mysc : 0.f)) * mynorm;
            }
        }

        if (lane < KP) {
            coef[lane][0] = alpha;
#pragma unroll
            for (int s = 0; s < NS; ++s) coef[lane][1 + s] = beta[s];
        }
    }
    __syncthreads();

    // ---- reconstruct p_k = alpha*p0_k + sum_s beta[s]*fe_s; publish + blend ----
    if (wave < KP) {
        const int k = wave;
        float alpha = coef[k][0];
        float bt[NS];
#pragma unroll
        for (int s = 0; s < NS; ++s) bt[s] = coef[k][1 + s];

        float4 p[3];
#pragma unroll
        for (int j4 = 0; j4 < 3; ++j4) {
            float4 a = *(const float4*)&p0l[k * CC + j4 * 256 + lane * 4];
            float4 acc;
            acc.x = alpha * a.x; acc.y = alpha * a.y; acc.z = alpha * a.z; acc.w = alpha * a.w;
#pragma unroll
            for (int s = 0; s < NS; ++s) {
                float4 fv = *(const float4*)&fe[s * CC + j4 * 256 + lane * 4];
                acc.x = fmaf(bt[s], fv.x, acc.x);
                acc.y = fmaf(bt[s], fv.y, acc.y);
                acc.z = fmaf(bt[s], fv.z, acc.z);
                acc.w = fmaf(bt[s], fv.w, acc.w);
            }
            p[j4] = acc;
        }

        // publish refined protos for the loss kernel
#pragma unroll
        for (int j4 = 0; j4 < 3; ++j4)
            *(float4*)&pout[k * CC + j4 * 256 + lane * 4] = p[j4];

        // blend epilogue: out row = safe_norm(0.7*p0 + 0.3*p)
        float4 vv4[3]; float ss2 = 0.f;
#pragma unroll
        for (int j4 = 0; j4 < 3; ++j4) {
            float4 pz = *(const float4*)&p0l[k * CC + j4 * 256 + lane * 4];
            vv4[j4].x = 0.7f * pz.x + 0.3f * p[j4].x;
            vv4[j4].y = 0.7f * pz.y + 0.3f * p[j4].y;
            vv4[j4].z = 0.7f * pz.z + 0.3f * p[j4].z;
            vv4[j4].w = 0.7f * pz.w + 0.3f * p[j4].w;
            ss2 = fmaf(vv4[j4].x, vv4[j4].x, ss2);
            ss2 = fmaf(vv4[j4].y, vv4[j4].y, ss2);
            ss2 = fmaf(vv4[j4].z, vv4[j4].z, ss2);
            ss2 = fmaf(vv4[j4].w, vv4[j4].w, ss2);
        }
#pragma unroll
        for (int m2 = 1; m2 < 64; m2 <<= 1) ss2 += __shfl_xor(ss2, m2, 64);
        float inv2 = 1.f / fmaxf(sqrtf(ss2), 1e-8f);
        float* orow = out + 1 + (side * KP + k) * CC;
#pragma unroll
        for (int j4 = 0; j4 < 3; ++j4) {
            float4 o4;
            o4.x = vv4[j4].x * inv2; o4.y = vv4[j4].y * inv2;
            o4.z = vv4[j4].z * inv2; o4.w = vv4[j4].w * inv2;
            *(float4*)&orow[j4 * 256 + lane * 4] = o4;
        }
    }
}

// ---------------- K3: loss (1 block, 16 waves) ----------------
__global__ __launch_bounds__(1024) void k_loss(const float* __restrict__ feats,
                                               const float* __restrict__ pfg,
                                               const float* __restrict__ pbg,
                                               float* __restrict__ out) {
    __shared__ float dots3[NS * 30];   // [s][g*10+k]: g=0 pos@pfg, g=1 neg@pfg, g=2 pos@pbg
    __shared__ float mp[NS], mn[NS], infon[NS];
    int tid = threadIdx.x, wave = tid >> 6, lane = tid & 63;

    for (int pid = wave; pid < 360; pid += 16) {
        int g = pid / 120, rr = pid % 120, s = rr / KP, k = rr % KP;
        const float4* a4 = (const float4*)(feats + ((g == 1 ? NS + s : s) * CC) + lane * 12);
        const float4* b4 = (const float4*)((g == 2 ? pbg : pfg) + k * CC + lane * 12);
        float acc = 0.f;
#pragma unroll
        for (int j = 0; j < 3; ++j) {
            float4 a = a4[j], b = b4[j];
            acc += a.x * b.x + a.y * b.y + a.z * b.z + a.w * b.w;
        }
#pragma unroll
        for (int m2 = 1; m2 < 64; m2 <<= 1) acc += __shfl_xor(acc, m2, 64);
        if (lane == 0) dots3[s * 30 + g * 10 + k] = acc;
    }
    __syncthreads();

    if (tid < NS) {
        const float* d = &dots3[tid * 30];
        float maxp = d[0], maxn = d[10];
#pragma unroll
        for (int k = 1; k < KP; ++k) { maxp = fmaxf(maxp, d[k]); maxn = fmaxf(maxn, d[10 + k]); }
        mp[tid] = maxp; mn[tid] = maxn;

        float x[KP], y[KP];
#pragma unroll
        for (int k = 0; k < KP; ++k) { x[k] = d[k] / 0.07f; y[k] = d[20 + k] / 0.07f; }
        float m10 = x[0];
#pragma unroll
        for (int k = 1; k < KP; ++k) m10 = fmaxf(m10, x[k]);
        float se = 0.f;
#pragma unroll
        for (int k = 0; k < KP; ++k) se += expf(x[k] - m10);
        float numer = logf(se) + m10;
        float m20 = m10;
#pragma unroll
        for (int k = 0; k < KP; ++k) m20 = fmaxf(m20, y[k]);
        float se2 = 0.f;
#pragma unroll
        for (int k = 0; k < KP; ++k) se2 += expf(x[k] - m20);
#pragma unroll
        for (int k = 0; k < KP; ++k) se2 += expf(y[k] - m20);
        float denom = logf(se2) + m20;
        infon[tid] = numer - denom;
    }
    __syncthreads();
    if (tid == 0) {
        float sp = 0.f, sn = 0.f, si = 0.f;
        for (int s = 0; s < NS; ++s) { sp += mp[s]; sn += mn[s]; si += infon[s]; }
        sp /= 12.f; sn /= 12.f; si /= 12.f;
        float loss = fmaxf(0.2f + sn - sp, 0.f) + 0.25f * (-si);
        out[0] = loss;
    }
}

extern "C" void kernel_launch(void* const* d_in, const int* in_sizes, int n_in,
                              void* d_out, int out_size, void* d_ws, size_t ws_size,
                              hipStream_t stream) {
    const float* fg = (const float*)d_in[0];   // [10,768]
    const float* bg = (const float*)d_in[1];   // [10,768]
    const float* F  = (const float*)d_in[2];   // [8,768,64,64]
    const float* M  = (const float*)d_in[3];   // [8,1,64,64]
    float* out = (float*)d_out;                // [1 + 7680 + 7680]

    float* w    = (float*)d_ws;
    ull*   cand = (ull*)(w + WS_CAND);
    float* fea  = w + WS_FEATS;
    float* pfg  = w + WS_PFG;
    float* pbg  = w + WS_PBG;

    k_scores      <<<NBLK, 1024, 0, stream>>>(fg, bg, F, M, cand);
    k_refine_fused<<<2, 1024, 0, stream>>>(cand, F, fg, bg, pfg, pbg, fea, out);
    k_loss        <<<1, 1024, 0, stream>>>(fea, pfg, pbg, out);
}